// Round 1
// baseline (1319.684 us; speedup 1.0000x reference)
//
#include <hip/hip_runtime.h>

// Problem constants
#define B_  8
#define N_  128
#define D_  512
#define H_  8
#define DK_ 64
#define FF_ 2048
#define L_  2
#define EPS_ 1e-5f

#define BND  (B_*N_*D_)     // 524288
#define BNN  (B_*N_*N_)     // 131072
#define BNFF (B_*N_*FF_)    // 2097152

// ---------------------------------------------------------------------------
// edge_bias[b,i,j] = mean_d edge_features[b,i,j,d]   (one wave per row of 512)
// ---------------------------------------------------------------------------
__global__ __launch_bounds__(256) void edge_mean_kernel(
    const float* __restrict__ ef, float* __restrict__ eb)
{
    int wid  = (blockIdx.x * blockDim.x + threadIdx.x) >> 6;   // wave id = row
    int lane = threadIdx.x & 63;
    if (wid >= BNN) return;
    const float* p = ef + (long)wid * D_;
    float4 a = *(const float4*)&p[lane * 4];
    float4 b = *(const float4*)&p[256 + lane * 4];
    float s = a.x + a.y + a.z + a.w + b.x + b.y + b.z + b.w;
    #pragma unroll
    for (int off = 32; off; off >>= 1) s += __shfl_xor(s, off);
    if (lane == 0) eb[wid] = s * (1.0f / (float)D_);
}

// ---------------------------------------------------------------------------
// adj_norm[b,i,j] = (adj[b,i,j] + I) / max(rowsum, 1)
// ---------------------------------------------------------------------------
__global__ __launch_bounds__(128) void adj_norm_kernel(
    const float* __restrict__ adj, float* __restrict__ an)
{
    int bi = blockIdx.x;            // b*128 + i
    int j  = threadIdx.x;           // 0..127
    int i  = bi & (N_ - 1);
    const float* row = adj + (long)bi * N_;
    float v = row[j] + (j == i ? 1.0f : 0.0f);
    float s = v;
    #pragma unroll
    for (int off = 32; off; off >>= 1) s += __shfl_xor(s, off);
    __shared__ float partial[2];
    if ((threadIdx.x & 63) == 0) partial[threadIdx.x >> 6] = s;
    __syncthreads();
    float tot = partial[0] + partial[1];
    tot = fmaxf(tot, 1.0f);
    an[(long)bi * N_ + j] = v / tot;
}

// ---------------------------------------------------------------------------
// Generic tiled f32 GEMM: C[z] = act(A[z] @ W[z] + bias), tiles 64x64x16,
// 256 threads, 4x4 micro-tile per thread. M%64==0, N%64==0, K%16==0.
// ---------------------------------------------------------------------------
__global__ __launch_bounds__(256) void gemm_kernel(
    const float* __restrict__ A, const float* __restrict__ W,
    const float* __restrict__ bias, float* __restrict__ C,
    int M, int N, int K,
    long sA, long sW, long sC, int relu)
{
    __shared__ float As[16][64];    // transposed A tile
    __shared__ float Bs[16][64];

    int tid = threadIdx.x;
    int bx = blockIdx.x, by = blockIdx.y, bz = blockIdx.z;
    const float* Ab = A + (long)bz * sA;
    const float* Wb = W + (long)bz * sW;
    float*       Cb = C + (long)bz * sC;

    int tx = tid & 15, ty = tid >> 4;           // 16x16 thread grid
    int arow = tid >> 2, acol = (tid & 3) * 4;  // A tile load map (64x16)
    int brow = tid >> 4, bcol = (tid & 15) * 4; // B tile load map (16x64)

    float acc[4][4] = {};

    for (int k0 = 0; k0 < K; k0 += 16) {
        float4 av = *(const float4*)&Ab[(long)(by * 64 + arow) * K + k0 + acol];
        float4 bv = *(const float4*)&Wb[(long)(k0 + brow) * N + bx * 64 + bcol];
        __syncthreads();
        As[acol + 0][arow] = av.x;
        As[acol + 1][arow] = av.y;
        As[acol + 2][arow] = av.z;
        As[acol + 3][arow] = av.w;
        *(float4*)&Bs[brow][bcol] = bv;
        __syncthreads();
        #pragma unroll
        for (int kk = 0; kk < 16; ++kk) {
            float a0 = As[kk][ty * 4 + 0];
            float a1 = As[kk][ty * 4 + 1];
            float a2 = As[kk][ty * 4 + 2];
            float a3 = As[kk][ty * 4 + 3];
            float4 b = *(float4*)&Bs[kk][tx * 4];
            acc[0][0] += a0 * b.x; acc[0][1] += a0 * b.y; acc[0][2] += a0 * b.z; acc[0][3] += a0 * b.w;
            acc[1][0] += a1 * b.x; acc[1][1] += a1 * b.y; acc[1][2] += a1 * b.z; acc[1][3] += a1 * b.w;
            acc[2][0] += a2 * b.x; acc[2][1] += a2 * b.y; acc[2][2] += a2 * b.z; acc[2][3] += a2 * b.w;
            acc[3][0] += a3 * b.x; acc[3][1] += a3 * b.y; acc[3][2] += a3 * b.z; acc[3][3] += a3 * b.w;
        }
    }

    int col = bx * 64 + tx * 4;
    float4 bo = {0.f, 0.f, 0.f, 0.f};
    if (bias) bo = *(const float4*)&bias[col];
    #pragma unroll
    for (int i = 0; i < 4; ++i) {
        int row = by * 64 + ty * 4 + i;
        float4 o;
        o.x = acc[i][0] + bo.x;
        o.y = acc[i][1] + bo.y;
        o.z = acc[i][2] + bo.z;
        o.w = acc[i][3] + bo.w;
        if (relu) {
            o.x = fmaxf(o.x, 0.f); o.y = fmaxf(o.y, 0.f);
            o.z = fmaxf(o.z, 0.f); o.w = fmaxf(o.w, 0.f);
        }
        *(float4*)&Cb[(long)row * N + col] = o;
    }
}

// ---------------------------------------------------------------------------
// Attention: per (b,h) block-group, scores = q@k^T*scale + edge_bias,
// softmax, ctx = attn@v.  Grid (B*H, 4 row-groups), 256 threads.
// ---------------------------------------------------------------------------
#define LDP 129
__global__ __launch_bounds__(256) void attn_kernel(
    const float* __restrict__ q, const float* __restrict__ k,
    const float* __restrict__ v, const float* __restrict__ eb,
    float* __restrict__ ctx)
{
    __shared__ float KT[DK_][LDP];     // K^T : KT[d][j]
    __shared__ float Vs[N_][DK_];      // V   : Vs[j][d]
    __shared__ float qs[2][DK_];
    __shared__ float ps[2][N_];
    __shared__ float red[2][2];
    __shared__ float cpar[2][2][DK_];

    int bh = blockIdx.x;               // 0..63
    int rg = blockIdx.y;               // 0..3 (32 rows each)
    int b  = bh >> 3, hh = bh & 7;
    int t  = threadIdx.x;

    // stage K^T and V for this (b,h)
    {
        int d  = t & 63;
        int jb = t >> 6;               // 0..3
        const float* kb = k + ((long)b * N_) * D_ + hh * DK_;
        const float* vb = v + ((long)b * N_) * D_ + hh * DK_;
        for (int j = jb; j < N_; j += 4) {
            KT[d][j] = kb[(long)j * D_ + d];
            Vs[j][d] = vb[(long)j * D_ + d];
        }
    }
    __syncthreads();

    int sub  = t >> 7;                 // which of the 2 concurrent rows
    int j    = t & 127;                // score column
    int lane = t & 63;
    int wh   = (t >> 6) & 1;           // wave-half within the 128-thread group
    int d    = t & 63;
    const float scale = 0.125f;        // 1/sqrt(64)

    for (int it = 0; it < 16; ++it) {
        int row0 = rg * 32 + it * 2;
        if (t < 128)
            qs[t >> 6][t & 63] =
                q[((long)b * N_ + row0 + (t >> 6)) * D_ + hh * DK_ + (t & 63)];
        __syncthreads();

        int row = row0 + sub;
        float s = 0.f;
        #pragma unroll
        for (int dd = 0; dd < DK_; ++dd) s += qs[sub][dd] * KT[dd][j];
        s = s * scale + eb[((long)b * N_ + row) * N_ + j];

        // max over the 128 columns (2 waves)
        float m = s;
        #pragma unroll
        for (int off = 32; off; off >>= 1) m = fmaxf(m, __shfl_xor(m, off));
        if (lane == 0) red[sub][wh] = m;
        __syncthreads();
        m = fmaxf(red[sub][0], red[sub][1]);

        float p  = expf(s - m);
        float su = p;
        #pragma unroll
        for (int off = 32; off; off >>= 1) su += __shfl_xor(su, off);
        __syncthreads();               // red reuse guard
        if (lane == 0) red[sub][wh] = su;
        __syncthreads();
        su = red[sub][0] + red[sub][1];

        ps[sub][j] = p / su;
        __syncthreads();

        // ctx: each wave-half accumulates 64 of the 128 columns
        float acc = 0.f;
        int j0 = wh * 64;
        #pragma unroll
        for (int jj = 0; jj < 64; ++jj) acc += ps[sub][j0 + jj] * Vs[j0 + jj][d];
        cpar[sub][wh][d] = acc;
        __syncthreads();
        if (wh == 0)
            ctx[((long)b * N_ + row) * D_ + hh * DK_ + d] =
                cpar[sub][0][d] + cpar[sub][1][d];
        __syncthreads();
    }
}

// ---------------------------------------------------------------------------
// x = LayerNorm(x + y) * g + b   (one wave per row of 512)
// ---------------------------------------------------------------------------
__global__ __launch_bounds__(64) void ln_residual_kernel(
    float* __restrict__ x, const float* __restrict__ y,
    const float* __restrict__ g, const float* __restrict__ bb)
{
    int row  = blockIdx.x;
    int lane = threadIdx.x;
    float* xr = x + (long)row * D_;
    const float* yr = y + (long)row * D_;

    float4 a0 = *(const float4*)&xr[lane * 4];
    float4 a1 = *(const float4*)&xr[256 + lane * 4];
    float4 b0 = *(const float4*)&yr[lane * 4];
    float4 b1 = *(const float4*)&yr[256 + lane * 4];

    float v0[8] = {a0.x + b0.x, a0.y + b0.y, a0.z + b0.z, a0.w + b0.w,
                   a1.x + b1.x, a1.y + b1.y, a1.z + b1.z, a1.w + b1.w};

    float s1 = 0.f, s2 = 0.f;
    #pragma unroll
    for (int i = 0; i < 8; ++i) { s1 += v0[i]; s2 += v0[i] * v0[i]; }
    #pragma unroll
    for (int off = 32; off; off >>= 1) {
        s1 += __shfl_xor(s1, off);
        s2 += __shfl_xor(s2, off);
    }
    float mean = s1 * (1.0f / (float)D_);
    float var  = s2 * (1.0f / (float)D_) - mean * mean;
    float rstd = rsqrtf(var + EPS_);

    float4 g0 = *(const float4*)&g[lane * 4];
    float4 g1 = *(const float4*)&g[256 + lane * 4];
    float4 q0 = *(const float4*)&bb[lane * 4];
    float4 q1 = *(const float4*)&bb[256 + lane * 4];

    float4 o0, o1;
    o0.x = (v0[0] - mean) * rstd * g0.x + q0.x;
    o0.y = (v0[1] - mean) * rstd * g0.y + q0.y;
    o0.z = (v0[2] - mean) * rstd * g0.z + q0.z;
    o0.w = (v0[3] - mean) * rstd * g0.w + q0.w;
    o1.x = (v0[4] - mean) * rstd * g1.x + q1.x;
    o1.y = (v0[5] - mean) * rstd * g1.y + q1.y;
    o1.z = (v0[6] - mean) * rstd * g1.z + q1.z;
    o1.w = (v0[7] - mean) * rstd * g1.w + q1.w;

    *(float4*)&xr[lane * 4]       = o0;
    *(float4*)&xr[256 + lane * 4] = o1;
}

// ---------------------------------------------------------------------------
extern "C" void kernel_launch(void* const* d_in, const int* in_sizes, int n_in,
                              void* d_out, int out_size, void* d_ws, size_t ws_size,
                              hipStream_t stream)
{
    const float* node = (const float*)d_in[0];
    const float* edge = (const float*)d_in[1];
    const float* adj  = (const float*)d_in[2];
    const float* Wq = (const float*)d_in[3];
    const float* Wk = (const float*)d_in[4];
    const float* Wv = (const float*)d_in[5];
    const float* Wo = (const float*)d_in[6];
    const float* Wg = (const float*)d_in[7];
    const float* Wf1 = (const float*)d_in[8];
    const float* Wf2 = (const float*)d_in[9];
    const float* bq = (const float*)d_in[10];
    const float* bk = (const float*)d_in[11];
    const float* bv = (const float*)d_in[12];
    const float* bo = (const float*)d_in[13];
    const float* bg = (const float*)d_in[14];
    const float* bf1 = (const float*)d_in[15];
    const float* bf2 = (const float*)d_in[16];
    const float* ln1g = (const float*)d_in[17];
    const float* ln1b = (const float*)d_in[18];
    const float* ln2g = (const float*)d_in[19];
    const float* ln2b = (const float*)d_in[20];
    const float* ln3g = (const float*)d_in[21];
    const float* ln3b = (const float*)d_in[22];

    float* x  = (float*)d_out;          // running activation lives in d_out
    float* ws = (float*)d_ws;
    float* eb   = ws;                   // BNN
    float* an   = eb + BNN;             // BNN
    float* q    = an + BNN;             // BND
    float* kk   = q + BND;              // BND
    float* vv   = kk + BND;             // BND
    float* ctx  = vv + BND;             // BND
    float* hbuf = q;                    // BNFF, aliases q..ctx (dead during FFN)
    float* tbuf = ctx + BND;            // BND

    // x = node_features
    hipMemcpyAsync(x, node, (size_t)BND * sizeof(float),
                   hipMemcpyDeviceToDevice, stream);

    // hoisted precomputes
    edge_mean_kernel<<<BNN / 4, 256, 0, stream>>>(edge, eb);
    adj_norm_kernel<<<B_ * N_, 128, 0, stream>>>(adj, an);

    const int M = B_ * N_;  // 1024

    for (int l = 0; l < L_; ++l) {
        const float* wq = Wq + (long)l * D_ * D_;
        const float* wk = Wk + (long)l * D_ * D_;
        const float* wv = Wv + (long)l * D_ * D_;
        const float* wo = Wo + (long)l * D_ * D_;
        const float* wg = Wg + (long)l * D_ * D_;
        const float* wf1 = Wf1 + (long)l * D_ * FF_;
        const float* wf2 = Wf2 + (long)l * FF_ * D_;

        // q,k,v projections
        gemm_kernel<<<dim3(D_ / 64, M / 64, 1), 256, 0, stream>>>(
            x, wq, bq + l * D_, q, M, D_, D_, 0, 0, 0, 0);
        gemm_kernel<<<dim3(D_ / 64, M / 64, 1), 256, 0, stream>>>(
            x, wk, bk + l * D_, kk, M, D_, D_, 0, 0, 0, 0);
        gemm_kernel<<<dim3(D_ / 64, M / 64, 1), 256, 0, stream>>>(
            x, wv, bv + l * D_, vv, M, D_, D_, 0, 0, 0, 0);

        // attention
        attn_kernel<<<dim3(B_ * H_, 4, 1), 256, 0, stream>>>(q, kk, vv, eb, ctx);

        // output projection + LN1
        gemm_kernel<<<dim3(D_ / 64, M / 64, 1), 256, 0, stream>>>(
            ctx, wo, bo + l * D_, tbuf, M, D_, D_, 0, 0, 0, 0);
        ln_residual_kernel<<<M, 64, 0, stream>>>(x, tbuf, ln1g + l * D_, ln1b + l * D_);

        // GCN aggregation: agg[b] = adj_norm[b] @ x[b]  (batched)
        gemm_kernel<<<dim3(D_ / 64, N_ / 64, B_), 256, 0, stream>>>(
            an, x, nullptr, tbuf, N_, D_, N_,
            (long)N_ * N_, (long)N_ * D_, (long)N_ * D_, 0);
        // relu(agg @ Wg + bg)
        gemm_kernel<<<dim3(D_ / 64, M / 64, 1), 256, 0, stream>>>(
            tbuf, wg, bg + l * D_, ctx, M, D_, D_, 0, 0, 0, 1);
        ln_residual_kernel<<<M, 64, 0, stream>>>(x, ctx, ln2g + l * D_, ln2b + l * D_);

        // FFN
        gemm_kernel<<<dim3(FF_ / 64, M / 64, 1), 256, 0, stream>>>(
            x, wf1, bf1 + l * FF_, hbuf, M, FF_, D_, 0, 0, 0, 1);
        gemm_kernel<<<dim3(D_ / 64, M / 64, 1), 256, 0, stream>>>(
            hbuf, wf2, bf2 + l * D_, tbuf, M, D_, FF_, 0, 0, 0, 0);
        ln_residual_kernel<<<M, 64, 0, stream>>>(x, tbuf, ln3g + l * D_, ln3b + l * D_);
    }
}

// Round 9
// 1066.391 us; speedup vs baseline: 1.2375x; 1.2375x over previous
//
#include <hip/hip_runtime.h>

// Problem constants
#define B_  8
#define N_  128
#define D_  512
#define H_  8
#define DK_ 64
#define FF_ 2048
#define L_  2
#define EPS_ 1e-5f

#define BND  (B_*N_*D_)     // 524288
#define BNN  (B_*N_*N_)     // 131072
#define BNFF (B_*N_*FF_)    // 2097152
#define DD   (D_*D_)        // 262144
#define DFF  (D_*FF_)       // 1048576
#define LAYER_SHORTS (10L*DD + 4L*DFF)

typedef __attribute__((ext_vector_type(8))) short short8;
typedef __attribute__((ext_vector_type(4))) float f32x4;

__device__ __forceinline__ unsigned short bf16h(float f) {
    unsigned u = __float_as_uint(f);
    return (unsigned short)((u + 0x7FFFu + ((u >> 16) & 1u)) >> 16);
}
__device__ __forceinline__ float bf16f(unsigned short h) {
    return __uint_as_float((unsigned)h << 16);
}

// ---------------------------------------------------------------------------
// edge_bias[b,i,j] = mean_d edge_features[b,i,j,d]   (one wave per row of 512)
// ---------------------------------------------------------------------------
__global__ __launch_bounds__(256) void edge_mean_kernel(
    const float* __restrict__ ef, float* __restrict__ eb)
{
    int wid  = (blockIdx.x * blockDim.x + threadIdx.x) >> 6;   // wave id = row
    int lane = threadIdx.x & 63;
    if (wid >= BNN) return;
    const float* p = ef + (long)wid * D_;
    float4 a = *(const float4*)&p[lane * 4];
    float4 b = *(const float4*)&p[256 + lane * 4];
    float s = a.x + a.y + a.z + a.w + b.x + b.y + b.z + b.w;
    #pragma unroll
    for (int off = 32; off; off >>= 1) s += __shfl_xor(s, off);
    if (lane == 0) eb[wid] = s * (1.0f / (float)D_);
}

// ---------------------------------------------------------------------------
// adj_norm[b,i,j] = (adj[b,i,j] + I) / max(rowsum, 1)
// ---------------------------------------------------------------------------
__global__ __launch_bounds__(128) void adj_norm_kernel(
    const float* __restrict__ adj, float* __restrict__ an)
{
    int bi = blockIdx.x;            // b*128 + i
    int j  = threadIdx.x;           // 0..127
    int i  = bi & (N_ - 1);
    const float* row = adj + (long)bi * N_;
    float v = row[j] + (j == i ? 1.0f : 0.0f);
    float s = v;
    #pragma unroll
    for (int off = 32; off; off >>= 1) s += __shfl_xor(s, off);
    __shared__ float partial[2];
    if ((threadIdx.x & 63) == 0) partial[threadIdx.x >> 6] = s;
    __syncthreads();
    float tot = partial[0] + partial[1];
    tot = fmaxf(tot, 1.0f);
    an[(long)bi * N_ + j] = v / tot;
}

// ---------------------------------------------------------------------------
// Weight convert + transpose: W (K x N f32) -> WT_hi, WT_lo (N x K bf16-bits)
// 64x64 tiles via LDS.
// ---------------------------------------------------------------------------
__global__ __launch_bounds__(256) void wconv_kernel(
    const float* __restrict__ W, unsigned short* __restrict__ Whi,
    unsigned short* __restrict__ Wlo, int K, int N)
{
    __shared__ ushort2 tile[64][65];
    int t = threadIdx.x;
    int k0 = blockIdx.y << 6, n0 = blockIdx.x << 6;
    #pragma unroll
    for (int p = 0; p < 4; ++p) {
        int k = (t >> 4) + (p << 4);
        int n = (t & 15) << 2;
        float4 v = *(const float4*)&W[(long)(k0 + k) * N + n0 + n];
        float vv[4] = {v.x, v.y, v.z, v.w};
        #pragma unroll
        for (int j = 0; j < 4; ++j) {
            unsigned short h = bf16h(vv[j]);
            unsigned short l = bf16h(vv[j] - bf16f(h));
            tile[k][n + j] = make_ushort2(h, l);
        }
    }
    __syncthreads();
    #pragma unroll
    for (int p = 0; p < 4; ++p) {
        int n = (t >> 4) + (p << 4);
        int k = (t & 15) << 2;
        ushort2 e0 = tile[k][n], e1 = tile[k + 1][n];
        ushort2 e2 = tile[k + 2][n], e3 = tile[k + 3][n];
        *(ushort4*)&Whi[(long)(n0 + n) * K + k0 + k] = make_ushort4(e0.x, e1.x, e2.x, e3.x);
        *(ushort4*)&Wlo[(long)(n0 + n) * K + k0 + k] = make_ushort4(e0.y, e1.y, e2.y, e3.y);
    }
}

// ---------------------------------------------------------------------------
// MFMA GEMM with bf16 hi/lo split (3 terms -> ~f32 accuracy).
// C[z] (M x N f32) = act(A (M x K f32) @ W[z] + bias[z])
// W given pre-transposed: WT[n][k] hi then lo, contiguous per z (wstride shorts).
// Tile 64x64x32; 4 waves; wave w owns rows w*16..w*16+15, all 64 cols.
// ---------------------------------------------------------------------------
__global__ __launch_bounds__(256) void gemm_mfma_kernel(
    const float* __restrict__ A,
    const unsigned short* __restrict__ WTbase, long wstride,
    const float* __restrict__ bias0, const float* __restrict__ bias1,
    const float* __restrict__ bias2,
    float* __restrict__ C, long cstride,
    int M, int N, int K, int relu)
{
    __shared__ __align__(16) unsigned short Ah[64][40];
    __shared__ __align__(16) unsigned short Al[64][40];

    int t = threadIdx.x;
    int z = blockIdx.z;
    const unsigned short* Whi = WTbase + (long)z * wstride;
    const unsigned short* Wlo = Whi + (long)N * K;
    const float* bias = (z == 0) ? bias0 : (z == 1 ? bias1 : bias2);
    float* Cb = C + (long)z * cstride;

    int m0 = blockIdx.y << 6, n0 = blockIdx.x << 6;
    int wv = t >> 6, lane = t & 63;
    int lr = lane & 15, lk = lane >> 4;

    // A staging map: each thread owns row sr, k-span [sk, sk+8) of the 64x32 tile
    int sr = t >> 2;                 // 0..63
    int sk = (t & 3) << 3;           // 0,8,16,24
    const float* Ap = &A[(long)(m0 + sr) * K + sk];

    f32x4 acc[4] = {{0.f,0.f,0.f,0.f},{0.f,0.f,0.f,0.f},
                    {0.f,0.f,0.f,0.f},{0.f,0.f,0.f,0.f}};

    for (int k0 = 0; k0 < K; k0 += 32) {
        float4 va = *(const float4*)(Ap + k0);
        float4 vb = *(const float4*)(Ap + k0 + 4);
        float f[8] = {va.x, va.y, va.z, va.w, vb.x, vb.y, vb.z, vb.w};
        unsigned short hh[8], ll[8];
        #pragma unroll
        for (int i = 0; i < 8; ++i) {
            hh[i] = bf16h(f[i]);
            ll[i] = bf16h(f[i] - bf16f(hh[i]));
        }
        __syncthreads();                          // previous-iter LDS reads done
        *(ushort4*)&Ah[sr][sk]     = make_ushort4(hh[0], hh[1], hh[2], hh[3]);
        *(ushort4*)&Ah[sr][sk + 4] = make_ushort4(hh[4], hh[5], hh[6], hh[7]);
        *(ushort4*)&Al[sr][sk]     = make_ushort4(ll[0], ll[1], ll[2], ll[3]);
        *(ushort4*)&Al[sr][sk + 4] = make_ushort4(ll[4], ll[5], ll[6], ll[7]);
        __syncthreads();

        short8 ah = *(const short8*)&Ah[(wv << 4) + lr][lk << 3];
        short8 al = *(const short8*)&Al[(wv << 4) + lr][lk << 3];
        #pragma unroll
        for (int nf = 0; nf < 4; ++nf) {
            long off = (long)(n0 + (nf << 4) + lr) * K + k0 + (lk << 3);
            short8 bh = *(const short8*)(Whi + off);
            short8 bl = *(const short8*)(Wlo + off);
            acc[nf] = __builtin_amdgcn_mfma_f32_16x16x32_bf16(ah, bh, acc[nf], 0, 0, 0);
            acc[nf] = __builtin_amdgcn_mfma_f32_16x16x32_bf16(ah, bl, acc[nf], 0, 0, 0);
            acc[nf] = __builtin_amdgcn_mfma_f32_16x16x32_bf16(al, bh, acc[nf], 0, 0, 0);
        }
    }

    #pragma unroll
    for (int nf = 0; nf < 4; ++nf) {
        int col = n0 + (nf << 4) + lr;
        float bi = bias ? bias[col] : 0.f;
        #pragma unroll
        for (int r = 0; r < 4; ++r) {
            int row = m0 + (wv << 4) + (lk << 2) + r;
            float o = acc[nf][r] + bi;
            if (relu) o = fmaxf(o, 0.f);
            Cb[(long)row * N + col] = o;
        }
    }
}

// ---------------------------------------------------------------------------
// f32 vector GEMM (kept for GCN aggregation: A,B both runtime f32, tiny)
// ---------------------------------------------------------------------------
__global__ __launch_bounds__(256) void gemm_kernel(
    const float* __restrict__ A, const float* __restrict__ W,
    const float* __restrict__ bias, float* __restrict__ C,
    int M, int N, int K,
    long sA, long sW, long sC, int relu)
{
    __shared__ float As[16][64];
    __shared__ float Bs[16][64];

    int tid = threadIdx.x;
    int bx = blockIdx.x, by = blockIdx.y, bz = blockIdx.z;
    const float* Ab = A + (long)bz * sA;
    const float* Wb = W + (long)bz * sW;
    float*       Cb = C + (long)bz * sC;

    int tx = tid & 15, ty = tid >> 4;
    int arow = tid >> 2, acol = (tid & 3) * 4;
    int brow = tid >> 4, bcol = (tid & 15) * 4;

    float acc[4][4] = {};

    for (int k0 = 0; k0 < K; k0 += 16) {
        float4 av = *(const float4*)&Ab[(long)(by * 64 + arow) * K + k0 + acol];
        float4 bv = *(const float4*)&Wb[(long)(k0 + brow) * N + bx * 64 + bcol];
        __syncthreads();
        As[acol + 0][arow] = av.x;
        As[acol + 1][arow] = av.y;
        As[acol + 2][arow] = av.z;
        As[acol + 3][arow] = av.w;
        *(float4*)&Bs[brow][bcol] = bv;
        __syncthreads();
        #pragma unroll
        for (int kk = 0; kk < 16; ++kk) {
            float a0 = As[kk][ty * 4 + 0];
            float a1 = As[kk][ty * 4 + 1];
            float a2 = As[kk][ty * 4 + 2];
            float a3 = As[kk][ty * 4 + 3];
            float4 b = *(float4*)&Bs[kk][tx * 4];
            acc[0][0] += a0 * b.x; acc[0][1] += a0 * b.y; acc[0][2] += a0 * b.z; acc[0][3] += a0 * b.w;
            acc[1][0] += a1 * b.x; acc[1][1] += a1 * b.y; acc[1][2] += a1 * b.z; acc[1][3] += a1 * b.w;
            acc[2][0] += a2 * b.x; acc[2][1] += a2 * b.y; acc[2][2] += a2 * b.z; acc[2][3] += a2 * b.w;
            acc[3][0] += a3 * b.x; acc[3][1] += a3 * b.y; acc[3][2] += a3 * b.z; acc[3][3] += a3 * b.w;
        }
    }

    int col = bx * 64 + tx * 4;
    float4 bo = {0.f, 0.f, 0.f, 0.f};
    if (bias) bo = *(const float4*)&bias[col];
    #pragma unroll
    for (int i = 0; i < 4; ++i) {
        int row = by * 64 + ty * 4 + i;
        float4 o;
        o.x = acc[i][0] + bo.x;
        o.y = acc[i][1] + bo.y;
        o.z = acc[i][2] + bo.z;
        o.w = acc[i][3] + bo.w;
        if (relu) {
            o.x = fmaxf(o.x, 0.f); o.y = fmaxf(o.y, 0.f);
            o.z = fmaxf(o.z, 0.f); o.w = fmaxf(o.w, 0.f);
        }
        *(float4*)&Cb[(long)row * N + col] = o;
    }
}

// ---------------------------------------------------------------------------
// Attention (unchanged)
// ---------------------------------------------------------------------------
#define LDP 129
__global__ __launch_bounds__(256) void attn_kernel(
    const float* __restrict__ q, const float* __restrict__ k,
    const float* __restrict__ v, const float* __restrict__ eb,
    float* __restrict__ ctx)
{
    __shared__ float KT[DK_][LDP];
    __shared__ float Vs[N_][DK_];
    __shared__ float qs[2][DK_];
    __shared__ float ps[2][N_];
    __shared__ float red[2][2];
    __shared__ float cpar[2][2][DK_];

    int bh = blockIdx.x;
    int rg = blockIdx.y;
    int b  = bh >> 3, hh = bh & 7;
    int t  = threadIdx.x;

    {
        int d  = t & 63;
        int jb = t >> 6;
        const float* kb = k + ((long)b * N_) * D_ + hh * DK_;
        const float* vb = v + ((long)b * N_) * D_ + hh * DK_;
        for (int j = jb; j < N_; j += 4) {
            KT[d][j] = kb[(long)j * D_ + d];
            Vs[j][d] = vb[(long)j * D_ + d];
        }
    }
    __syncthreads();

    int sub  = t >> 7;
    int j    = t & 127;
    int lane = t & 63;
    int wh   = (t >> 6) & 1;
    int d    = t & 63;
    const float scale = 0.125f;

    for (int it = 0; it < 16; ++it) {
        int row0 = rg * 32 + it * 2;
        if (t < 128)
            qs[t >> 6][t & 63] =
                q[((long)b * N_ + row0 + (t >> 6)) * D_ + hh * DK_ + (t & 63)];
        __syncthreads();

        int row = row0 + sub;
        float s = 0.f;
        #pragma unroll
        for (int dd = 0; dd < DK_; ++dd) s += qs[sub][dd] * KT[dd][j];
        s = s * scale + eb[((long)b * N_ + row) * N_ + j];

        float m = s;
        #pragma unroll
        for (int off = 32; off; off >>= 1) m = fmaxf(m, __shfl_xor(m, off));
        if (lane == 0) red[sub][wh] = m;
        __syncthreads();
        m = fmaxf(red[sub][0], red[sub][1]);

        float p  = expf(s - m);
        float su = p;
        #pragma unroll
        for (int off = 32; off; off >>= 1) su += __shfl_xor(su, off);
        __syncthreads();
        if (lane == 0) red[sub][wh] = su;
        __syncthreads();
        su = red[sub][0] + red[sub][1];

        ps[sub][j] = p / su;
        __syncthreads();

        float acc = 0.f;
        int j0 = wh * 64;
        #pragma unroll
        for (int jj = 0; jj < 64; ++jj) acc += ps[sub][j0 + jj] * Vs[j0 + jj][d];
        cpar[sub][wh][d] = acc;
        __syncthreads();
        if (wh == 0)
            ctx[((long)b * N_ + row) * D_ + hh * DK_ + d] =
                cpar[sub][0][d] + cpar[sub][1][d];
        __syncthreads();
    }
}

// ---------------------------------------------------------------------------
// x = LayerNorm(x + y) * g + b   (one wave per row of 512)
// ---------------------------------------------------------------------------
__global__ __launch_bounds__(64) void ln_residual_kernel(
    float* __restrict__ x, const float* __restrict__ y,
    const float* __restrict__ g, const float* __restrict__ bb)
{
    int row  = blockIdx.x;
    int lane = threadIdx.x;
    float* xr = x + (long)row * D_;
    const float* yr = y + (long)row * D_;

    float4 a0 = *(const float4*)&xr[lane * 4];
    float4 a1 = *(const float4*)&xr[256 + lane * 4];
    float4 b0 = *(const float4*)&yr[lane * 4];
    float4 b1 = *(const float4*)&yr[256 + lane * 4];

    float v0[8] = {a0.x + b0.x, a0.y + b0.y, a0.z + b0.z, a0.w + b0.w,
                   a1.x + b1.x, a1.y + b1.y, a1.z + b1.z, a1.w + b1.w};

    float s1 = 0.f, s2 = 0.f;
    #pragma unroll
    for (int i = 0; i < 8; ++i) { s1 += v0[i]; s2 += v0[i] * v0[i]; }
    #pragma unroll
    for (int off = 32; off; off >>= 1) {
        s1 += __shfl_xor(s1, off);
        s2 += __shfl_xor(s2, off);
    }
    float mean = s1 * (1.0f / (float)D_);
    float var  = s2 * (1.0f / (float)D_) - mean * mean;
    float rstd = rsqrtf(var + EPS_);

    float4 g0 = *(const float4*)&g[lane * 4];
    float4 g1 = *(const float4*)&g[256 + lane * 4];
    float4 q0 = *(const float4*)&bb[lane * 4];
    float4 q1 = *(const float4*)&bb[256 + lane * 4];

    float4 o0, o1;
    o0.x = (v0[0] - mean) * rstd * g0.x + q0.x;
    o0.y = (v0[1] - mean) * rstd * g0.y + q0.y;
    o0.z = (v0[2] - mean) * rstd * g0.z + q0.z;
    o0.w = (v0[3] - mean) * rstd * g0.w + q0.w;
    o1.x = (v0[4] - mean) * rstd * g1.x + q1.x;
    o1.y = (v0[5] - mean) * rstd * g1.y + q1.y;
    o1.z = (v0[6] - mean) * rstd * g1.z + q1.z;
    o1.w = (v0[7] - mean) * rstd * g1.w + q1.w;

    *(float4*)&xr[lane * 4]       = o0;
    *(float4*)&xr[256 + lane * 4] = o1;
}

// ---------------------------------------------------------------------------
extern "C" void kernel_launch(void* const* d_in, const int* in_sizes, int n_in,
                              void* d_out, int out_size, void* d_ws, size_t ws_size,
                              hipStream_t stream)
{
    const float* node = (const float*)d_in[0];
    const float* edge = (const float*)d_in[1];
    const float* adj  = (const float*)d_in[2];
    const float* Wq = (const float*)d_in[3];
    const float* Wk = (const float*)d_in[4];
    const float* Wv = (const float*)d_in[5];
    const float* Wo = (const float*)d_in[6];
    const float* Wg = (const float*)d_in[7];
    const float* Wf1 = (const float*)d_in[8];
    const float* Wf2 = (const float*)d_in[9];
    const float* bq = (const float*)d_in[10];
    const float* bk = (const float*)d_in[11];
    const float* bv = (const float*)d_in[12];
    const float* bo = (const float*)d_in[13];
    const float* bg = (const float*)d_in[14];
    const float* bf1 = (const float*)d_in[15];
    const float* bf2 = (const float*)d_in[16];
    const float* ln1g = (const float*)d_in[17];
    const float* ln1b = (const float*)d_in[18];
    const float* ln2g = (const float*)d_in[19];
    const float* ln2b = (const float*)d_in[20];
    const float* ln3g = (const float*)d_in[21];
    const float* ln3b = (const float*)d_in[22];

    float* x  = (float*)d_out;
    float* ws = (float*)d_ws;
    float* eb   = ws;                   // BNN
    float* an   = eb + BNN;             // BNN
    float* q    = an + BNN;             // BND
    float* kk   = q + BND;              // BND
    float* vv   = kk + BND;             // BND
    float* ctx  = vv + BND;             // BND
    float* hbuf = q;                    // BNFF, aliases q..ctx (dead during FFN)
    float* tbuf = ctx + BND;            // BND
    unsigned short* wcv = (unsigned short*)(tbuf + BND);   // converted weights

    hipMemcpyAsync(x, node, (size_t)BND * sizeof(float),
                   hipMemcpyDeviceToDevice, stream);

    edge_mean_kernel<<<BNN / 4, 256, 0, stream>>>(edge, eb);
    adj_norm_kernel<<<B_ * N_, 128, 0, stream>>>(adj, an);

    // ---- weight conversion (hi/lo bf16, transposed) ----
    for (int l = 0; l < L_; ++l) {
        unsigned short* wl = wcv + (long)l * LAYER_SHORTS;
        unsigned short* WQT = wl;
        unsigned short* WKT = wl + 2L * DD;
        unsigned short* WVT = wl + 4L * DD;
        unsigned short* WOT = wl + 6L * DD;
        unsigned short* WGT = wl + 8L * DD;
        unsigned short* WF1T = wl + 10L * DD;
        unsigned short* WF2T = wl + 10L * DD + 2L * DFF;
        wconv_kernel<<<dim3(8, 8), 256, 0, stream>>>(Wq + (long)l * DD, WQT, WQT + DD, D_, D_);
        wconv_kernel<<<dim3(8, 8), 256, 0, stream>>>(Wk + (long)l * DD, WKT, WKT + DD, D_, D_);
        wconv_kernel<<<dim3(8, 8), 256, 0, stream>>>(Wv + (long)l * DD, WVT, WVT + DD, D_, D_);
        wconv_kernel<<<dim3(8, 8), 256, 0, stream>>>(Wo + (long)l * DD, WOT, WOT + DD, D_, D_);
        wconv_kernel<<<dim3(8, 8), 256, 0, stream>>>(Wg + (long)l * DD, WGT, WGT + DD, D_, D_);
        wconv_kernel<<<dim3(32, 8), 256, 0, stream>>>(Wf1 + (long)l * DFF, WF1T, WF1T + DFF, D_, FF_);
        wconv_kernel<<<dim3(8, 32), 256, 0, stream>>>(Wf2 + (long)l * DFF, WF2T, WF2T + DFF, FF_, D_);
    }

    const int M = B_ * N_;  // 1024

    for (int l = 0; l < L_; ++l) {
        unsigned short* wl = wcv + (long)l * LAYER_SHORTS;
        unsigned short* WQT = wl;
        unsigned short* WOT = wl + 6L * DD;
        unsigned short* WGT = wl + 8L * DD;
        unsigned short* WF1T = wl + 10L * DD;
        unsigned short* WF2T = wl + 10L * DD + 2L * DFF;

        // q,k,v projections (batched over z: writes q, kk, vv contiguously)
        gemm_mfma_kernel<<<dim3(D_ / 64, M / 64, 3), 256, 0, stream>>>(
            x, WQT, 2L * DD, bq + l * D_, bk + l * D_, bv + l * D_,
            q, (long)BND, M, D_, D_, 0);

        attn_kernel<<<dim3(B_ * H_, 4, 1), 256, 0, stream>>>(q, kk, vv, eb, ctx);

        // output projection + LN1
        gemm_mfma_kernel<<<dim3(D_ / 64, M / 64, 1), 256, 0, stream>>>(
            ctx, WOT, 0, bo + l * D_, bo + l * D_, bo + l * D_,
            tbuf, 0, M, D_, D_, 0);
        ln_residual_kernel<<<M, 64, 0, stream>>>(x, tbuf, ln1g + l * D_, ln1b + l * D_);

        // GCN aggregation (f32 vector GEMM, batched over B)
        gemm_kernel<<<dim3(D_ / 64, N_ / 64, B_), 256, 0, stream>>>(
            an, x, nullptr, tbuf, N_, D_, N_,
            (long)N_ * N_, (long)N_ * D_, (long)N_ * D_, 0);
        // relu(agg @ Wg + bg)
        gemm_mfma_kernel<<<dim3(D_ / 64, M / 64, 1), 256, 0, stream>>>(
            tbuf, WGT, 0, bg + l * D_, bg + l * D_, bg + l * D_,
            ctx, 0, M, D_, D_, 1);
        ln_residual_kernel<<<M, 64, 0, stream>>>(x, ctx, ln2g + l * D_, ln2b + l * D_);

        // FFN
        gemm_mfma_kernel<<<dim3(FF_ / 64, M / 64, 1), 256, 0, stream>>>(
            x, WF1T, 0, bf1 + l * FF_, bf1 + l * FF_, bf1 + l * FF_,
            hbuf, 0, M, FF_, D_, 1);
        gemm_mfma_kernel<<<dim3(D_ / 64, M / 64, 1), 256, 0, stream>>>(
            hbuf, WF2T, 0, bf2 + l * D_, bf2 + l * D_, bf2 + l * D_,
            tbuf, 0, M, D_, FF_, 0);
        ln_residual_kernel<<<M, 64, 0, stream>>>(x, tbuf, ln3g + l * D_, ln3b + l * D_);
    }
}

// Round 11
// 890.996 us; speedup vs baseline: 1.4811x; 1.1969x over previous
//
#include <hip/hip_runtime.h>

// Problem constants
#define B_  8
#define N_  128
#define D_  512
#define H_  8
#define DK_ 64
#define FF_ 2048
#define L_  2
#define EPS_ 1e-5f

#define BND  (B_*N_*D_)     // 524288
#define BNN  (B_*N_*N_)     // 131072
#define BNFF (B_*N_*FF_)    // 2097152
#define DD   (D_*D_)        // 262144
#define DFF  (D_*FF_)       // 1048576
#define LAYER_SHORTS (10L*DD + 4L*DFF)

typedef __attribute__((ext_vector_type(8))) short short8;
typedef __attribute__((ext_vector_type(4))) float f32x4;

__device__ __forceinline__ unsigned short bf16h(float f) {
    unsigned u = __float_as_uint(f);
    return (unsigned short)((u + 0x7FFFu + ((u >> 16) & 1u)) >> 16);
}
__device__ __forceinline__ float bf16f(unsigned short h) {
    return __uint_as_float((unsigned)h << 16);
}

// ---------------------------------------------------------------------------
// edge_bias[b,i,j] = mean_d edge_features[b,i,j,d]   (one wave per row of 512)
// ---------------------------------------------------------------------------
__global__ __launch_bounds__(256) void edge_mean_kernel(
    const float* __restrict__ ef, float* __restrict__ eb)
{
    int wid  = (blockIdx.x * blockDim.x + threadIdx.x) >> 6;   // wave id = row
    int lane = threadIdx.x & 63;
    if (wid >= BNN) return;
    const float* p = ef + (long)wid * D_;
    float4 a = *(const float4*)&p[lane * 4];
    float4 b = *(const float4*)&p[256 + lane * 4];
    float s = a.x + a.y + a.z + a.w + b.x + b.y + b.z + b.w;
    #pragma unroll
    for (int off = 32; off; off >>= 1) s += __shfl_xor(s, off);
    if (lane == 0) eb[wid] = s * (1.0f / (float)D_);
}

// ---------------------------------------------------------------------------
// adj_norm[b,i,j] = (adj[b,i,j] + I) / max(rowsum, 1)
// ---------------------------------------------------------------------------
__global__ __launch_bounds__(128) void adj_norm_kernel(
    const float* __restrict__ adj, float* __restrict__ an)
{
    int bi = blockIdx.x;            // b*128 + i
    int j  = threadIdx.x;           // 0..127
    int i  = bi & (N_ - 1);
    const float* row = adj + (long)bi * N_;
    float v = row[j] + (j == i ? 1.0f : 0.0f);
    float s = v;
    #pragma unroll
    for (int off = 32; off; off >>= 1) s += __shfl_xor(s, off);
    __shared__ float partial[2];
    if ((threadIdx.x & 63) == 0) partial[threadIdx.x >> 6] = s;
    __syncthreads();
    float tot = partial[0] + partial[1];
    tot = fmaxf(tot, 1.0f);
    an[(long)bi * N_ + j] = v / tot;
}

// ---------------------------------------------------------------------------
// Weight convert helpers (shared tile body)
// ---------------------------------------------------------------------------
__device__ __forceinline__ void wconv_tile(
    const float* __restrict__ W, unsigned short* __restrict__ Whi,
    unsigned short* __restrict__ Wlo, int K, int N, int k0, int n0, int t)
{
    __shared__ ushort2 tile[64][65];
    #pragma unroll
    for (int p = 0; p < 4; ++p) {
        int k = (t >> 4) + (p << 4);
        int n = (t & 15) << 2;
        float4 v = *(const float4*)&W[(long)(k0 + k) * N + n0 + n];
        float vv[4] = {v.x, v.y, v.z, v.w};
        #pragma unroll
        for (int j = 0; j < 4; ++j) {
            unsigned short h = bf16h(vv[j]);
            unsigned short l = bf16h(vv[j] - bf16f(h));
            tile[k][n + j] = make_ushort2(h, l);
        }
    }
    __syncthreads();
    #pragma unroll
    for (int p = 0; p < 4; ++p) {
        int n = (t >> 4) + (p << 4);
        int k = (t & 15) << 2;
        ushort2 e0 = tile[k][n], e1 = tile[k + 1][n];
        ushort2 e2 = tile[k + 2][n], e3 = tile[k + 3][n];
        *(ushort4*)&Whi[(long)(n0 + n) * K + k0 + k] = make_ushort4(e0.x, e1.x, e2.x, e3.x);
        *(ushort4*)&Wlo[(long)(n0 + n) * K + k0 + k] = make_ushort4(e0.y, e1.y, e2.y, e3.y);
    }
}

// All 10 D x D weight matrices in one dispatch: z = ti*2 + l, ti in 0..4.
__global__ __launch_bounds__(256) void wconv10_kernel(
    const float* __restrict__ Wq, const float* __restrict__ Wk,
    const float* __restrict__ Wv, const float* __restrict__ Wo,
    const float* __restrict__ Wg, unsigned short* __restrict__ wcv)
{
    int z  = blockIdx.z;
    int ti = z >> 1, l = z & 1;
    const float* src = (ti == 0) ? Wq : (ti == 1) ? Wk : (ti == 2) ? Wv
                       : (ti == 3) ? Wo : Wg;
    src += (long)l * DD;
    unsigned short* dh = wcv + (long)l * LAYER_SHORTS + (long)ti * 2L * DD;
    wconv_tile(src, dh, dh + DD, D_, D_,
               blockIdx.y << 6, blockIdx.x << 6, threadIdx.x);
}

// Generic z-strided convert (for Wf1 / Wf2, z = layer)
__global__ __launch_bounds__(256) void wconvz_kernel(
    const float* __restrict__ W, long sstride,
    unsigned short* __restrict__ dbase, long dstride, int K, int N)
{
    int z = blockIdx.z;
    const float* src = W + (long)z * sstride;
    unsigned short* dh = dbase + (long)z * dstride;
    wconv_tile(src, dh, dh + (long)K * N, K, N,
               blockIdx.y << 6, blockIdx.x << 6, threadIdx.x);
}

// ---------------------------------------------------------------------------
// MFMA GEMM v2: 32x64 tile, BK=32, reg-prefetch A + double-buffered LDS
// (1 barrier / K-step). 4 waves: wave w -> rows (w&1)*16, cols (w>>1)*32.
// C[z] = act(A @ WT[z]^T + bias[z]); hi/lo bf16 split, 3 MFMA terms.
// ---------------------------------------------------------------------------
__global__ __launch_bounds__(256) void gemm_mfma_kernel(
    const float* __restrict__ A,
    const unsigned short* __restrict__ WTbase, long wstride,
    const float* __restrict__ bias0, const float* __restrict__ bias1,
    const float* __restrict__ bias2,
    float* __restrict__ C, long cstride,
    int M, int N, int K, int relu)
{
    __shared__ __align__(16) unsigned short Ah[2][32][40];
    __shared__ __align__(16) unsigned short Al[2][32][40];

    int t = threadIdx.x;
    int z = blockIdx.z;
    const unsigned short* Whi = WTbase + (long)z * wstride;
    const unsigned short* Wlo = Whi + (long)N * K;
    const float* bias = (z == 0) ? bias0 : (z == 1 ? bias1 : bias2);
    float* Cb = C + (long)z * cstride;

    int m0 = blockIdx.y << 5, n0 = blockIdx.x << 6;
    int wv = t >> 6, lane = t & 63;
    int lr = lane & 15, lk = lane >> 4;
    int r0 = (wv & 1) << 4;          // 0 / 16
    int c0 = (wv >> 1) << 5;         // 0 / 32

    // A staging: thread owns row sr, k-span [sk, sk+4) -> one float4 / K-step
    int sr = t >> 3;                 // 0..31
    int sk = (t & 7) << 2;           // 0,4,...,28
    const float* Ap = &A[(long)(m0 + sr) * K + sk];

    f32x4 acc[2] = {{0.f,0.f,0.f,0.f},{0.f,0.f,0.f,0.f}};

    // prologue: stage k0 = 0 into buffer 0
    float4 va = *(const float4*)(Ap);
    {
        unsigned short h0 = bf16h(va.x), h1 = bf16h(va.y),
                       h2 = bf16h(va.z), h3 = bf16h(va.w);
        unsigned short l0 = bf16h(va.x - bf16f(h0));
        unsigned short l1 = bf16h(va.y - bf16f(h1));
        unsigned short l2 = bf16h(va.z - bf16f(h2));
        unsigned short l3 = bf16h(va.w - bf16f(h3));
        *(ushort4*)&Ah[0][sr][sk] = make_ushort4(h0, h1, h2, h3);
        *(ushort4*)&Al[0][sr][sk] = make_ushort4(l0, l1, l2, l3);
    }
    __syncthreads();

    int cur = 0;
    for (int k0 = 0; k0 < K; k0 += 32) {
        bool more = (k0 + 32) < K;
        if (more) va = *(const float4*)(Ap + k0 + 32);   // prefetch next A

        short8 ah = *(const short8*)&Ah[cur][r0 + lr][lk << 3];
        short8 al = *(const short8*)&Al[cur][r0 + lr][lk << 3];
        #pragma unroll
        for (int nf = 0; nf < 2; ++nf) {
            long off = (long)(n0 + c0 + (nf << 4) + lr) * K + k0 + (lk << 3);
            short8 bh = *(const short8*)(Whi + off);
            short8 bl = *(const short8*)(Wlo + off);
            acc[nf] = __builtin_amdgcn_mfma_f32_16x16x32_bf16(ah, bh, acc[nf], 0, 0, 0);
            acc[nf] = __builtin_amdgcn_mfma_f32_16x16x32_bf16(ah, bl, acc[nf], 0, 0, 0);
            acc[nf] = __builtin_amdgcn_mfma_f32_16x16x32_bf16(al, bh, acc[nf], 0, 0, 0);
        }

        if (more) {
            unsigned short h0 = bf16h(va.x), h1 = bf16h(va.y),
                           h2 = bf16h(va.z), h3 = bf16h(va.w);
            unsigned short l0 = bf16h(va.x - bf16f(h0));
            unsigned short l1 = bf16h(va.y - bf16f(h1));
            unsigned short l2 = bf16h(va.z - bf16f(h2));
            unsigned short l3 = bf16h(va.w - bf16f(h3));
            int nb = cur ^ 1;
            *(ushort4*)&Ah[nb][sr][sk] = make_ushort4(h0, h1, h2, h3);
            *(ushort4*)&Al[nb][sr][sk] = make_ushort4(l0, l1, l2, l3);
            __syncthreads();
            cur = nb;
        }
    }

    #pragma unroll
    for (int nf = 0; nf < 2; ++nf) {
        int col = n0 + c0 + (nf << 4) + lr;
        float bi = bias ? bias[col] : 0.f;
        #pragma unroll
        for (int r = 0; r < 4; ++r) {
            int row = m0 + r0 + (lk << 2) + r;
            float o = acc[nf][r] + bi;
            if (relu) o = fmaxf(o, 0.f);
            Cb[(long)row * N + col] = o;
        }
    }
}

// ---------------------------------------------------------------------------
// f32 vector GEMM (kept for GCN aggregation: A,B both runtime f32, tiny)
// ---------------------------------------------------------------------------
__global__ __launch_bounds__(256) void gemm_kernel(
    const float* __restrict__ A, const float* __restrict__ W,
    const float* __restrict__ bias, float* __restrict__ C,
    int M, int N, int K,
    long sA, long sW, long sC, int relu)
{
    __shared__ float As[16][64];
    __shared__ float Bs[16][64];

    int tid = threadIdx.x;
    int bx = blockIdx.x, by = blockIdx.y, bz = blockIdx.z;
    const float* Ab = A + (long)bz * sA;
    const float* Wb = W + (long)bz * sW;
    float*       Cb = C + (long)bz * sC;

    int tx = tid & 15, ty = tid >> 4;
    int arow = tid >> 2, acol = (tid & 3) * 4;
    int brow = tid >> 4, bcol = (tid & 15) * 4;

    float acc[4][4] = {};

    for (int k0 = 0; k0 < K; k0 += 16) {
        float4 av = *(const float4*)&Ab[(long)(by * 64 + arow) * K + k0 + acol];
        float4 bv = *(const float4*)&Wb[(long)(k0 + brow) * N + bx * 64 + bcol];
        __syncthreads();
        As[acol + 0][arow] = av.x;
        As[acol + 1][arow] = av.y;
        As[acol + 2][arow] = av.z;
        As[acol + 3][arow] = av.w;
        *(float4*)&Bs[brow][bcol] = bv;
        __syncthreads();
        #pragma unroll
        for (int kk = 0; kk < 16; ++kk) {
            float a0 = As[kk][ty * 4 + 0];
            float a1 = As[kk][ty * 4 + 1];
            float a2 = As[kk][ty * 4 + 2];
            float a3 = As[kk][ty * 4 + 3];
            float4 b = *(float4*)&Bs[kk][tx * 4];
            acc[0][0] += a0 * b.x; acc[0][1] += a0 * b.y; acc[0][2] += a0 * b.z; acc[0][3] += a0 * b.w;
            acc[1][0] += a1 * b.x; acc[1][1] += a1 * b.y; acc[1][2] += a1 * b.z; acc[1][3] += a1 * b.w;
            acc[2][0] += a2 * b.x; acc[2][1] += a2 * b.y; acc[2][2] += a2 * b.z; acc[2][3] += a2 * b.w;
            acc[3][0] += a3 * b.x; acc[3][1] += a3 * b.y; acc[3][2] += a3 * b.z; acc[3][3] += a3 * b.w;
        }
    }

    int col = bx * 64 + tx * 4;
    float4 bo = {0.f, 0.f, 0.f, 0.f};
    if (bias) bo = *(const float4*)&bias[col];
    #pragma unroll
    for (int i = 0; i < 4; ++i) {
        int row = by * 64 + ty * 4 + i;
        float4 o;
        o.x = acc[i][0] + bo.x;
        o.y = acc[i][1] + bo.y;
        o.z = acc[i][2] + bo.z;
        o.w = acc[i][3] + bo.w;
        if (relu) {
            o.x = fmaxf(o.x, 0.f); o.y = fmaxf(o.y, 0.f);
            o.z = fmaxf(o.z, 0.f); o.w = fmaxf(o.w, 0.f);
        }
        *(float4*)&Cb[(long)row * N + col] = o;
    }
}

// ---------------------------------------------------------------------------
// Attention (unchanged)
// ---------------------------------------------------------------------------
#define LDP 129
__global__ __launch_bounds__(256) void attn_kernel(
    const float* __restrict__ q, const float* __restrict__ k,
    const float* __restrict__ v, const float* __restrict__ eb,
    float* __restrict__ ctx)
{
    __shared__ float KT[DK_][LDP];
    __shared__ float Vs[N_][DK_];
    __shared__ float qs[2][DK_];
    __shared__ float ps[2][N_];
    __shared__ float red[2][2];
    __shared__ float cpar[2][2][DK_];

    int bh = blockIdx.x;
    int rg = blockIdx.y;
    int b  = bh >> 3, hh = bh & 7;
    int t  = threadIdx.x;

    {
        int d  = t & 63;
        int jb = t >> 6;
        const float* kb = k + ((long)b * N_) * D_ + hh * DK_;
        const float* vb = v + ((long)b * N_) * D_ + hh * DK_;
        for (int j = jb; j < N_; j += 4) {
            KT[d][j] = kb[(long)j * D_ + d];
            Vs[j][d] = vb[(long)j * D_ + d];
        }
    }
    __syncthreads();

    int sub  = t >> 7;
    int j    = t & 127;
    int lane = t & 63;
    int wh   = (t >> 6) & 1;
    int d    = t & 63;
    const float scale = 0.125f;

    for (int it = 0; it < 16; ++it) {
        int row0 = rg * 32 + it * 2;
        if (t < 128)
            qs[t >> 6][t & 63] =
                q[((long)b * N_ + row0 + (t >> 6)) * D_ + hh * DK_ + (t & 63)];
        __syncthreads();

        int row = row0 + sub;
        float s = 0.f;
        #pragma unroll
        for (int dd = 0; dd < DK_; ++dd) s += qs[sub][dd] * KT[dd][j];
        s = s * scale + eb[((long)b * N_ + row) * N_ + j];

        float m = s;
        #pragma unroll
        for (int off = 32; off; off >>= 1) m = fmaxf(m, __shfl_xor(m, off));
        if (lane == 0) red[sub][wh] = m;
        __syncthreads();
        m = fmaxf(red[sub][0], red[sub][1]);

        float p  = expf(s - m);
        float su = p;
        #pragma unroll
        for (int off = 32; off; off >>= 1) su += __shfl_xor(su, off);
        __syncthreads();
        if (lane == 0) red[sub][wh] = su;
        __syncthreads();
        su = red[sub][0] + red[sub][1];

        ps[sub][j] = p / su;
        __syncthreads();

        float acc = 0.f;
        int j0 = wh * 64;
        #pragma unroll
        for (int jj = 0; jj < 64; ++jj) acc += ps[sub][j0 + jj] * Vs[j0 + jj][d];
        cpar[sub][wh][d] = acc;
        __syncthreads();
        if (wh == 0)
            ctx[((long)b * N_ + row) * D_ + hh * DK_ + d] =
                cpar[sub][0][d] + cpar[sub][1][d];
        __syncthreads();
    }
}

// ---------------------------------------------------------------------------
// x = LayerNorm(x + y) * g + b   (one wave per row of 512)
// ---------------------------------------------------------------------------
__global__ __launch_bounds__(64) void ln_residual_kernel(
    float* __restrict__ x, const float* __restrict__ y,
    const float* __restrict__ g, const float* __restrict__ bb)
{
    int row  = blockIdx.x;
    int lane = threadIdx.x;
    float* xr = x + (long)row * D_;
    const float* yr = y + (long)row * D_;

    float4 a0 = *(const float4*)&xr[lane * 4];
    float4 a1 = *(const float4*)&xr[256 + lane * 4];
    float4 b0 = *(const float4*)&yr[lane * 4];
    float4 b1 = *(const float4*)&yr[256 + lane * 4];

    float v0[8] = {a0.x + b0.x, a0.y + b0.y, a0.z + b0.z, a0.w + b0.w,
                   a1.x + b1.x, a1.y + b1.y, a1.z + b1.z, a1.w + b1.w};

    float s1 = 0.f, s2 = 0.f;
    #pragma unroll
    for (int i = 0; i < 8; ++i) { s1 += v0[i]; s2 += v0[i] * v0[i]; }
    #pragma unroll
    for (int off = 32; off; off >>= 1) {
        s1 += __shfl_xor(s1, off);
        s2 += __shfl_xor(s2, off);
    }
    float mean = s1 * (1.0f / (float)D_);
    float var  = s2 * (1.0f / (float)D_) - mean * mean;
    float rstd = rsqrtf(var + EPS_);

    float4 g0 = *(const float4*)&g[lane * 4];
    float4 g1 = *(const float4*)&g[256 + lane * 4];
    float4 q0 = *(const float4*)&bb[lane * 4];
    float4 q1 = *(const float4*)&bb[256 + lane * 4];

    float4 o0, o1;
    o0.x = (v0[0] - mean) * rstd * g0.x + q0.x;
    o0.y = (v0[1] - mean) * rstd * g0.y + q0.y;
    o0.z = (v0[2] - mean) * rstd * g0.z + q0.z;
    o0.w = (v0[3] - mean) * rstd * g0.w + q0.w;
    o1.x = (v0[4] - mean) * rstd * g1.x + q1.x;
    o1.y = (v0[5] - mean) * rstd * g1.y + q1.y;
    o1.z = (v0[6] - mean) * rstd * g1.z + q1.z;
    o1.w = (v0[7] - mean) * rstd * g1.w + q1.w;

    *(float4*)&xr[lane * 4]       = o0;
    *(float4*)&xr[256 + lane * 4] = o1;
}

// ---------------------------------------------------------------------------
extern "C" void kernel_launch(void* const* d_in, const int* in_sizes, int n_in,
                              void* d_out, int out_size, void* d_ws, size_t ws_size,
                              hipStream_t stream)
{
    const float* node = (const float*)d_in[0];
    const float* edge = (const float*)d_in[1];
    const float* adj  = (const float*)d_in[2];
    const float* Wq = (const float*)d_in[3];
    const float* Wk = (const float*)d_in[4];
    const float* Wv = (const float*)d_in[5];
    const float* Wo = (const float*)d_in[6];
    const float* Wg = (const float*)d_in[7];
    const float* Wf1 = (const float*)d_in[8];
    const float* Wf2 = (const float*)d_in[9];
    const float* bq = (const float*)d_in[10];
    const float* bk = (const float*)d_in[11];
    const float* bv = (const float*)d_in[12];
    const float* bo = (const float*)d_in[13];
    const float* bg = (const float*)d_in[14];
    const float* bf1 = (const float*)d_in[15];
    const float* bf2 = (const float*)d_in[16];
    const float* ln1g = (const float*)d_in[17];
    const float* ln1b = (const float*)d_in[18];
    const float* ln2g = (const float*)d_in[19];
    const float* ln2b = (const float*)d_in[20];
    const float* ln3g = (const float*)d_in[21];
    const float* ln3b = (const float*)d_in[22];

    float* x  = (float*)d_out;
    float* ws = (float*)d_ws;
    float* eb   = ws;                   // BNN
    float* an   = eb + BNN;             // BNN
    float* q    = an + BNN;             // BND
    float* kk   = q + BND;              // BND
    float* vv   = kk + BND;             // BND
    float* ctx  = vv + BND;             // BND
    float* hbuf = q;                    // BNFF, aliases q..ctx (dead during FFN)
    float* tbuf = ctx + BND;            // BND
    unsigned short* wcv = (unsigned short*)(tbuf + BND);   // converted weights

    hipMemcpyAsync(x, node, (size_t)BND * sizeof(float),
                   hipMemcpyDeviceToDevice, stream);

    edge_mean_kernel<<<BNN / 4, 256, 0, stream>>>(edge, eb);
    adj_norm_kernel<<<B_ * N_, 128, 0, stream>>>(adj, an);

    // ---- weight conversion (hi/lo bf16, transposed): 3 dispatches ----
    wconv10_kernel<<<dim3(8, 8, 10), 256, 0, stream>>>(Wq, Wk, Wv, Wo, Wg, wcv);
    wconvz_kernel<<<dim3(32, 8, 2), 256, 0, stream>>>(
        Wf1, (long)DFF, wcv + 10L * DD, (long)LAYER_SHORTS, D_, FF_);
    wconvz_kernel<<<dim3(8, 32, 2), 256, 0, stream>>>(
        Wf2, (long)DFF, wcv + 10L * DD + 2L * DFF, (long)LAYER_SHORTS, FF_, D_);

    const int M = B_ * N_;  // 1024

    for (int l = 0; l < L_; ++l) {
        unsigned short* wl = wcv + (long)l * LAYER_SHORTS;
        unsigned short* WQT = wl;
        unsigned short* WOT = wl + 6L * DD;
        unsigned short* WGT = wl + 8L * DD;
        unsigned short* WF1T = wl + 10L * DD;
        unsigned short* WF2T = wl + 10L * DD + 2L * DFF;

        // q,k,v projections (batched over z: writes q, kk, vv contiguously)
        gemm_mfma_kernel<<<dim3(D_ / 64, M / 32, 3), 256, 0, stream>>>(
            x, WQT, 2L * DD, bq + l * D_, bk + l * D_, bv + l * D_,
            q, (long)BND, M, D_, D_, 0);

        attn_kernel<<<dim3(B_ * H_, 4, 1), 256, 0, stream>>>(q, kk, vv, eb, ctx);

        // output projection + LN1
        gemm_mfma_kernel<<<dim3(D_ / 64, M / 32, 1), 256, 0, stream>>>(
            ctx, WOT, 0, bo + l * D_, bo + l * D_, bo + l * D_,
            tbuf, 0, M, D_, D_, 0);
        ln_residual_kernel<<<M, 64, 0, stream>>>(x, tbuf, ln1g + l * D_, ln1b + l * D_);

        // GCN aggregation (f32 vector GEMM, batched over B)
        gemm_kernel<<<dim3(D_ / 64, N_ / 64, B_), 256, 0, stream>>>(
            an, x, nullptr, tbuf, N_, D_, N_,
            (long)N_ * N_, (long)N_ * D_, (long)N_ * D_, 0);
        // relu(agg @ Wg + bg)
        gemm_mfma_kernel<<<dim3(D_ / 64, M / 32, 1), 256, 0, stream>>>(
            tbuf, WGT, 0, bg + l * D_, bg + l * D_, bg + l * D_,
            ctx, 0, M, D_, D_, 1);
        ln_residual_kernel<<<M, 64, 0, stream>>>(x, ctx, ln2g + l * D_, ln2b + l * D_);

        // FFN
        gemm_mfma_kernel<<<dim3(FF_ / 64, M / 32, 1), 256, 0, stream>>>(
            x, WF1T, 0, bf1 + l * FF_, bf1 + l * FF_, bf1 + l * FF_,
            hbuf, 0, M, FF_, D_, 1);
        gemm_mfma_kernel<<<dim3(D_ / 64, M / 32, 1), 256, 0, stream>>>(
            hbuf, WF2T, 0, bf2 + l * D_, bf2 + l * D_, bf2 + l * D_,
            tbuf, 0, M, D_, FF_, 0);
        ln_residual_kernel<<<M, 64, 0, stream>>>(x, tbuf, ln3g + l * D_, ln3b + l * D_);
    }
}